// Round 4
// baseline (145.143 us; speedup 1.0000x reference)
//
#include <hip/hip_runtime.h>
#include <math.h>

// Problem constants (from reference): B=8, M=N=4096, C=3, f32.
constexpr int NB  = 8;
constexpr int M   = 4096;
constexpr int N   = 4096;
constexpr int NS  = 32;           // segments of the N loop
constexpr int SEG = N / NS;       // 128 points per segment
constexpr int TPB = 256;
constexpr int KA  = 16;           // a-points per thread (covers all of M)
constexpr int KP  = KA / 2;       // packed fp32 pairs

typedef float v2f __attribute__((ext_vector_type(2)));

// Fused kernel, grid = 2*NB*NS = 512 blocks.
// Phase 1 (all blocks): pmin[g][seg][a] = sa + min_{n in seg}(sb - 2 a.b)
//   using v_pk_fma_f32 packed math (2 query points per instruction).
// Phase 2 (last block per group g=dir*NB+batch): min over segs, clamp, sqrt,
//   mean-sum -> partial[g].
// Phase 3 (last group finisher): out[b] = (partial[b]+partial[8+b])/M.
// Counters are device-scope atomics; release/acquire via __threadfence
// (cross-XCD L2 non-coherence, G16). No spin-waits -> no deadlock risk.
__global__ __launch_bounds__(TPB, 2) void hausdorff_fused_kernel(
    const float* __restrict__ set1, const float* __restrict__ set2,
    float* __restrict__ pmin, float* __restrict__ partial,
    unsigned* __restrict__ ctr1, unsigned* __restrict__ ctr2,
    float* __restrict__ out)
{
    __shared__ float4 bpts[SEG];   // 2 KB: (-2x, -2y, -2z, |b|^2)
    __shared__ unsigned flag;
    __shared__ float red[TPB / 64];

    int bid   = blockIdx.x;
    int seg   = bid & (NS - 1);
    int g     = bid >> 5;          // dir*NB + batch, in [0,16)
    int batch = g & (NB - 1);
    int dir   = g >> 3;
    int tid   = threadIdx.x;

    const float* A  = dir ? set2 : set1;   // query set
    const float* Bs = dir ? set1 : set2;   // target set

    // ---- Phase 1: segment-min ----
    const float* src = Bs + ((size_t)batch * N + (size_t)seg * SEG) * 3;
    for (int i = tid; i < SEG; i += TPB) {
        float x = src[i*3+0], y = src[i*3+1], z = src[i*3+2];
        float sb = fmaf(z, z, fmaf(y, y, x * x));
        bpts[i] = make_float4(-2.0f * x, -2.0f * y, -2.0f * z, sb);
    }
    __syncthreads();

    // Query points in registers, packed in pairs: pair p holds a-points
    // (2p)*TPB+tid and (2p+1)*TPB+tid.
    v2f ax2[KP], ay2[KP], az2[KP], dmin2[KP];
    const float* abase = A + (size_t)batch * M * 3;
    #pragma unroll
    for (int p = 0; p < KP; ++p) {
        int a0 = (2*p)   * TPB + tid;
        int a1 = (2*p+1) * TPB + tid;
        ax2[p] = (v2f){abase[a0*3+0], abase[a1*3+0]};
        ay2[p] = (v2f){abase[a0*3+1], abase[a1*3+1]};
        az2[p] = (v2f){abase[a0*3+2], abase[a1*3+2]};
        dmin2[p] = (v2f){3.4e38f, 3.4e38f};
    }

    #pragma unroll 4
    for (int n = 0; n < SEG; ++n) {
        float4 b = bpts[n];            // broadcast ds_read_b128
        v2f bx = {b.x, b.x}, by = {b.y, b.y}, bz = {b.z, b.z}, bw = {b.w, b.w};
        #pragma unroll
        for (int p = 0; p < KP; ++p) {
            v2f t = __builtin_elementwise_fma(az2[p], bz, bw);
            t     = __builtin_elementwise_fma(ay2[p], by, t);
            t     = __builtin_elementwise_fma(ax2[p], bx, t);   // sb - 2 a.b
            dmin2[p] = __builtin_elementwise_min(dmin2[p], t);
        }
    }

    // Epilogue: add query-constant |a|^2, write coalesced [g][seg][a].
    float* outp = pmin + ((size_t)g * NS + seg) * M;
    #pragma unroll
    for (int p = 0; p < KP; ++p) {
        int a0 = (2*p)   * TPB + tid;
        int a1 = (2*p+1) * TPB + tid;
        float sa0 = fmaf(az2[p].x, az2[p].x, fmaf(ay2[p].x, ay2[p].x, ax2[p].x * ax2[p].x));
        float sa1 = fmaf(az2[p].y, az2[p].y, fmaf(ay2[p].y, ay2[p].y, ax2[p].y * ax2[p].y));
        outp[a0] = sa0 + dmin2[p].x;
        outp[a1] = sa1 + dmin2[p].y;
    }

    // ---- Publish & elect per-group reducer ----
    __syncthreads();               // drains vmcnt (stores complete)
    __threadfence();               // release pmin to device scope
    if (tid == 0) {
        unsigned old = __hip_atomic_fetch_add(&ctr1[g], 1u,
                          __ATOMIC_ACQ_REL, __HIP_MEMORY_SCOPE_AGENT);
        flag = (old == NS - 1) ? 1u : 0u;
    }
    __syncthreads();
    if (!flag) return;             // uniform per block
    __threadfence();               // acquire other blocks' pmin

    // ---- Phase 2: reduce this group's [NS][M] slice ----
    const float* base = pmin + (size_t)g * NS * M;
    float sum = 0.0f;
    for (int a = tid; a < M; a += TPB) {
        float m = 3.4e38f;
        #pragma unroll
        for (int s = 0; s < NS; ++s)
            m = fminf(m, base[(size_t)s * M + a]);   // coalesced per seg
        sum += sqrtf(fmaxf(m, 0.0f));
    }
    for (int off = 32; off > 0; off >>= 1)
        sum += __shfl_down(sum, off, 64);
    int lane = tid & 63, wv = tid >> 6;
    if (lane == 0) red[wv] = sum;
    __syncthreads();

    if (tid == 0) {
        float t = 0.0f;
        #pragma unroll
        for (int w = 0; w < TPB / 64; ++w) t += red[w];
        partial[g] = t;
        __threadfence();           // release partial
        unsigned old = __hip_atomic_fetch_add(ctr2, 1u,
                          __ATOMIC_ACQ_REL, __HIP_MEMORY_SCOPE_AGENT);
        flag = (old == 2 * NB - 1) ? 1u : 0u;
    }
    __syncthreads();
    if (!flag) return;
    __threadfence();               // acquire all partials

    // ---- Phase 3: final 8 outputs ----
    if (tid < NB)
        out[tid] = (partial[tid] + partial[NB + tid]) * (1.0f / (float)M);
}

extern "C" void kernel_launch(void* const* d_in, const int* in_sizes, int n_in,
                              void* d_out, int out_size, void* d_ws, size_t ws_size,
                              hipStream_t stream) {
    const float* set1 = (const float*)d_in[0];
    const float* set2 = (const float*)d_in[1];
    float* out = (float*)d_out;

    char* ws = (char*)d_ws;
    float*    pmin    = (float*)ws;                       // 2*NB*NS*M*4 = 8 MiB
    char*     aux     = ws + (size_t)2 * NB * NS * M * 4;
    float*    partial = (float*)aux;                      // 16 floats
    unsigned* ctr1    = (unsigned*)(aux + 64);            // 16 counters
    unsigned* ctr2    = (unsigned*)(aux + 128);           // 1 counter

    // Counters must be zero at every launch (d_ws poisoned once, not per call).
    hipMemsetAsync(aux, 0, 192, stream);

    hausdorff_fused_kernel<<<2 * NB * NS, TPB, 0, stream>>>(
        set1, set2, pmin, partial, ctr1, ctr2, out);
}

// Round 5
// 40.458 us; speedup vs baseline: 3.5875x; 3.5875x over previous
//
#include <hip/hip_runtime.h>
#include <math.h>

// Problem constants (from reference): B=8, M=N=4096, C=3, f32.
constexpr int NB   = 8;
constexpr int M    = 4096;
constexpr int N    = 4096;
constexpr int NS   = 32;           // segments of the N loop
constexpr int SEG  = N / NS;       // 128 points per segment
constexpr int TPB  = 256;
constexpr int KA   = 16;           // a-points per thread (covers all of M)
constexpr int RTPB = 1024;         // reduce-kernel threads

// Stage 1: pmin[g][seg][a] = sa + min_{n in seg} (sb - 2 a.b)
// Identity: min_b ||a-b||^2 = sa + min_b (sb - 2 a.b) -> 3 fma + 1 min / pair.
// VALU model: 128 n x 64 instr x 2 cyc x 2 waves/SIMD = 13.7 us.
// LDS broadcast (8 waves/CU x 12 cyc = 96 cyc/n) hidden under VALU (256 cyc/n).
// grid = 2*NB*NS = 512 blocks (2 blocks/CU).
__global__ __launch_bounds__(TPB, 2) void hausdorff_min_kernel(
    const float* __restrict__ set1, const float* __restrict__ set2,
    float* __restrict__ pmin)
{
    __shared__ float4 bpts[SEG];   // 2 KB: (-2x, -2y, -2z, |b|^2)

    int bid   = blockIdx.x;
    int seg   = bid & (NS - 1);
    int g     = bid >> 5;          // dir*NB + batch
    int batch = g & (NB - 1);
    int dir   = g >> 3;
    int tid   = threadIdx.x;

    const float* A  = dir ? set2 : set1;   // query set
    const float* Bs = dir ? set1 : set2;   // target set

    const float* src = Bs + ((size_t)batch * N + (size_t)seg * SEG) * 3;
    for (int i = tid; i < SEG; i += TPB) {
        float x = src[i*3+0], y = src[i*3+1], z = src[i*3+2];
        float sb = fmaf(z, z, fmaf(y, y, x * x));
        bpts[i] = make_float4(-2.0f * x, -2.0f * y, -2.0f * z, sb);
    }
    __syncthreads();

    float ax[KA], ay[KA], az[KA], dmin[KA];
    const float* abase = A + (size_t)batch * M * 3;
    #pragma unroll
    for (int k = 0; k < KA; ++k) {
        int ai = k * TPB + tid;
        ax[k] = abase[ai*3+0];
        ay[k] = abase[ai*3+1];
        az[k] = abase[ai*3+2];
        dmin[k] = 3.4e38f;
    }

    #pragma unroll 8
    for (int n = 0; n < SEG; ++n) {
        float4 b = bpts[n];            // broadcast ds_read_b128
        #pragma unroll
        for (int k = 0; k < KA; ++k) {
            float d2 = fmaf(ax[k], b.x, fmaf(ay[k], b.y, fmaf(az[k], b.z, b.w)));
            dmin[k] = fminf(dmin[k], d2);
        }
    }

    // Epilogue: add query-constant |a|^2, coalesced stores [g][seg][a].
    float* outp = pmin + ((size_t)g * NS + seg) * M;
    #pragma unroll
    for (int k = 0; k < KA; ++k) {
        int ai = k * TPB + tid;
        float sa = fmaf(az[k], az[k], fmaf(ay[k], ay[k], ax[k] * ax[k]));
        outp[ai] = sa + dmin[k];
    }
}

// Stage 2: one block per batch; both directions; min over segs (float4
// columns, fully coalesced), clamp, sqrt, block-sum -> out[b].
// grid = NB = 8 blocks x 1024 threads. 64 independent loads/thread for MLP.
__global__ __launch_bounds__(RTPB) void hausdorff_reduce_kernel(
    const float* __restrict__ pmin, float* __restrict__ out)
{
    int b = blockIdx.x;
    int t = threadIdx.x;               // float4 column index, 0..1023 (=M/4)

    float sum = 0.0f;
    #pragma unroll
    for (int dir = 0; dir < 2; ++dir) {
        const float4* base = reinterpret_cast<const float4*>(
            pmin + (size_t)(dir * NB + b) * NS * M);
        float4 mn = make_float4(3.4e38f, 3.4e38f, 3.4e38f, 3.4e38f);
        #pragma unroll 8
        for (int s = 0; s < NS; ++s) {
            float4 v = base[(size_t)s * (M/4) + t];
            mn.x = fminf(mn.x, v.x); mn.y = fminf(mn.y, v.y);
            mn.z = fminf(mn.z, v.z); mn.w = fminf(mn.w, v.w);
        }
        sum += sqrtf(fmaxf(mn.x, 0.0f)) + sqrtf(fmaxf(mn.y, 0.0f))
             + sqrtf(fmaxf(mn.z, 0.0f)) + sqrtf(fmaxf(mn.w, 0.0f));
    }

    for (int off = 32; off > 0; off >>= 1)
        sum += __shfl_down(sum, off, 64);

    __shared__ float red[RTPB / 64];
    if ((t & 63) == 0) red[t >> 6] = sum;
    __syncthreads();
    if (t == 0) {
        float tt = 0.0f;
        #pragma unroll
        for (int w = 0; w < RTPB / 64; ++w) tt += red[w];
        out[b] = tt * (1.0f / (float)M);   // (sum_dir0 + sum_dir1) / 4096
    }
}

extern "C" void kernel_launch(void* const* d_in, const int* in_sizes, int n_in,
                              void* d_out, int out_size, void* d_ws, size_t ws_size,
                              hipStream_t stream) {
    const float* set1 = (const float*)d_in[0];
    const float* set2 = (const float*)d_in[1];
    float* out  = (float*)d_out;
    float* pmin = (float*)d_ws;    // 2*NB*NS*M*4 = 8 MiB

    hausdorff_min_kernel<<<2 * NB * NS, TPB, 0, stream>>>(set1, set2, pmin);
    hausdorff_reduce_kernel<<<NB, RTPB, 0, stream>>>(pmin, out);
}

// Round 6
// 33.396 us; speedup vs baseline: 4.3461x; 1.2115x over previous
//
#include <hip/hip_runtime.h>
#include <math.h>

// Problem constants (from reference): B=8, M=N=4096, C=3, f32.
constexpr int NB   = 8;
constexpr int M    = 4096;
constexpr int N    = 4096;
constexpr int NS   = 16;           // segments of the N loop
constexpr int SEG  = N / NS;       // 256 points per segment
constexpr int TPB  = 512;
constexpr int KA   = 8;            // a-points per thread; TPB*KA = 4096 = M
constexpr int RTPB = 1024;         // reduce-kernel threads (= M/4 float4 cols)

// Stage 1: pmin[g][seg][a] = sa + min_{n in seg} (sb - 2 a.b)
// Identity: min_b ||a-b||^2 = sa + min_b (sb - 2 a.b) -> 3 fma + 1 min / pair.
// VALU model: 256 n x 32 instr x 2 cyc x 2 waves/SIMD = 13.7 us total.
// LDS broadcast: 8 waves/CU x 12 cyc = 96 cyc/n < VALU 128 cyc/n  -> hidden.
// grid = 2*NB*NS = 256 blocks (1 block/CU, 8 waves/CU, 2 waves/SIMD).
__global__ __launch_bounds__(TPB, 2) void hausdorff_min_kernel(
    const float* __restrict__ set1, const float* __restrict__ set2,
    float* __restrict__ pmin)
{
    __shared__ float4 bpts[SEG];   // 4 KB: (-2x, -2y, -2z, |b|^2)

    int bid   = blockIdx.x;
    int seg   = bid & (NS - 1);
    int g     = bid >> 4;          // dir*NB + batch
    int batch = g & (NB - 1);
    int dir   = g >> 3;
    int tid   = threadIdx.x;

    const float* A  = dir ? set2 : set1;   // query set
    const float* Bs = dir ? set1 : set2;   // target set

    // Cooperative load + transform of the n-segment into LDS.
    const float* src = Bs + ((size_t)batch * N + (size_t)seg * SEG) * 3;
    for (int i = tid; i < SEG; i += TPB) {
        float x = src[i*3+0], y = src[i*3+1], z = src[i*3+2];
        float sb = fmaf(z, z, fmaf(y, y, x * x));
        bpts[i] = make_float4(-2.0f * x, -2.0f * y, -2.0f * z, sb);
    }
    __syncthreads();

    // This thread's KA query points in registers (block covers all of M).
    float ax[KA], ay[KA], az[KA], dmin[KA];
    const float* abase = A + (size_t)batch * M * 3;
    #pragma unroll
    for (int k = 0; k < KA; ++k) {
        int ai = k * TPB + tid;
        ax[k] = abase[ai*3+0];
        ay[k] = abase[ai*3+1];
        az[k] = abase[ai*3+2];
        dmin[k] = 3.4e38f;
    }

    #pragma unroll 8
    for (int n = 0; n < SEG; ++n) {
        float4 b = bpts[n];            // broadcast ds_read_b128
        #pragma unroll
        for (int k = 0; k < KA; ++k) {
            float d2 = fmaf(ax[k], b.x, fmaf(ay[k], b.y, fmaf(az[k], b.z, b.w)));
            dmin[k] = fminf(dmin[k], d2);
        }
    }

    // Epilogue: add query-constant |a|^2, coalesced stores [g][seg][a].
    float* outp = pmin + ((size_t)g * NS + seg) * M;
    #pragma unroll
    for (int k = 0; k < KA; ++k) {
        int ai = k * TPB + tid;
        float sa = fmaf(az[k], az[k], fmaf(ay[k], ay[k], ax[k] * ax[k]));
        outp[ai] = sa + dmin[k];
    }
}

// Stage 2: one block per batch; both directions; min over 16 segs (float4
// columns, fully coalesced), clamp, sqrt, block-sum -> out[b].
// grid = NB = 8 blocks x 1024 threads; 32 independent b128 loads/thread.
__global__ __launch_bounds__(RTPB) void hausdorff_reduce_kernel(
    const float* __restrict__ pmin, float* __restrict__ out)
{
    int b = blockIdx.x;
    int t = threadIdx.x;               // float4 column index, 0..1023 (=M/4)

    float sum = 0.0f;
    #pragma unroll
    for (int dir = 0; dir < 2; ++dir) {
        const float4* base = reinterpret_cast<const float4*>(
            pmin + (size_t)(dir * NB + b) * NS * M);
        float4 mn = make_float4(3.4e38f, 3.4e38f, 3.4e38f, 3.4e38f);
        #pragma unroll 8
        for (int s = 0; s < NS; ++s) {
            float4 v = base[(size_t)s * (M/4) + t];
            mn.x = fminf(mn.x, v.x); mn.y = fminf(mn.y, v.y);
            mn.z = fminf(mn.z, v.z); mn.w = fminf(mn.w, v.w);
        }
        sum += sqrtf(fmaxf(mn.x, 0.0f)) + sqrtf(fmaxf(mn.y, 0.0f))
             + sqrtf(fmaxf(mn.z, 0.0f)) + sqrtf(fmaxf(mn.w, 0.0f));
    }

    for (int off = 32; off > 0; off >>= 1)
        sum += __shfl_down(sum, off, 64);

    __shared__ float red[RTPB / 64];
    if ((t & 63) == 0) red[t >> 6] = sum;
    __syncthreads();
    if (t == 0) {
        float tt = 0.0f;
        #pragma unroll
        for (int w = 0; w < RTPB / 64; ++w) tt += red[w];
        out[b] = tt * (1.0f / (float)M);   // (sum_dir0 + sum_dir1) / 4096
    }
}

extern "C" void kernel_launch(void* const* d_in, const int* in_sizes, int n_in,
                              void* d_out, int out_size, void* d_ws, size_t ws_size,
                              hipStream_t stream) {
    const float* set1 = (const float*)d_in[0];
    const float* set2 = (const float*)d_in[1];
    float* out  = (float*)d_out;
    float* pmin = (float*)d_ws;    // 2*NB*NS*M*4 = 4 MiB

    hausdorff_min_kernel<<<2 * NB * NS, TPB, 0, stream>>>(set1, set2, pmin);
    hausdorff_reduce_kernel<<<NB, RTPB, 0, stream>>>(pmin, out);
}

// Round 7
// 33.181 us; speedup vs baseline: 4.3742x; 1.0065x over previous
//
#include <hip/hip_runtime.h>
#include <math.h>

// Problem constants (from reference): B=8, M=N=4096, C=3, f32.
constexpr int NB   = 8;
constexpr int M    = 4096;
constexpr int N    = 4096;
constexpr int NS   = 32;           // segments of the N loop
constexpr int SEG  = N / NS;       // 128 points per segment
constexpr int TPB  = 256;
constexpr int KA   = 16;           // a-points per thread; TPB*KA = 4096 = M
constexpr int GPB  = 4;            // k2a blocks per group g
constexpr int CPB  = (M / 4) / GPB;// float4 columns per k2a block = 256

// Stage 1: pmin[g][seg][a] = sa + min_{n in seg} (sb - 2 a.b)
// Identity: min_b ||a-b||^2 = sa + min_b (sb - 2 a.b) -> 3 fma + 1 min / pair.
// Config: 512 blocks (2/CU), 16 waves/CU (4/SIMD).
//   VALU per n per CU: 16w x 64instr x 2cyc / 4SIMD = 512 cyc
//   LDS  per n per CU: 16w x 12cyc b128 broadcast    = 192 cyc  (2.7x headroom)
// VALU floor: 1.07e9 lane-ops / 7.86e13 = 13.7 us.
__global__ __launch_bounds__(TPB, 2) void hausdorff_min_kernel(
    const float* __restrict__ set1, const float* __restrict__ set2,
    float* __restrict__ pmin)
{
    __shared__ float4 bpts[SEG];   // 2 KB: (-2x, -2y, -2z, |b|^2)

    int bid   = blockIdx.x;
    int seg   = bid & (NS - 1);
    int g     = bid >> 5;          // dir*NB + batch
    int batch = g & (NB - 1);
    int dir   = g >> 3;
    int tid   = threadIdx.x;

    const float* A  = dir ? set2 : set1;   // query set
    const float* Bs = dir ? set1 : set2;   // target set

    // Cooperative load + transform of the n-segment into LDS.
    const float* src = Bs + ((size_t)batch * N + (size_t)seg * SEG) * 3;
    for (int i = tid; i < SEG; i += TPB) {
        float x = src[i*3+0], y = src[i*3+1], z = src[i*3+2];
        float sb = fmaf(z, z, fmaf(y, y, x * x));
        bpts[i] = make_float4(-2.0f * x, -2.0f * y, -2.0f * z, sb);
    }
    __syncthreads();

    // This thread's KA query points in registers (block covers all of M).
    float ax[KA], ay[KA], az[KA], dmin[KA];
    const float* abase = A + (size_t)batch * M * 3;
    #pragma unroll
    for (int k = 0; k < KA; ++k) {
        int ai = k * TPB + tid;
        ax[k] = abase[ai*3+0];
        ay[k] = abase[ai*3+1];
        az[k] = abase[ai*3+2];
        dmin[k] = 3.4e38f;
    }

    #pragma unroll 4
    for (int n = 0; n < SEG; ++n) {
        float4 b = bpts[n];            // broadcast ds_read_b128
        #pragma unroll
        for (int k = 0; k < KA; ++k) {
            float d2 = fmaf(ax[k], b.x, fmaf(ay[k], b.y, fmaf(az[k], b.z, b.w)));
            dmin[k] = fminf(dmin[k], d2);
        }
    }

    // Epilogue: add query-constant |a|^2, coalesced stores [g][seg][a].
    float* outp = pmin + ((size_t)g * NS + seg) * M;
    #pragma unroll
    for (int k = 0; k < KA; ++k) {
        int ai = k * TPB + tid;
        float sa = fmaf(az[k], az[k], fmaf(ay[k], ay[k], ax[k] * ax[k]));
        outp[ai] = sa + dmin[k];
    }
}

// Stage 2a: grid = 16*GPB = 64 blocks x 256 threads; one float4-column per
// thread (coalesced), min over 32 segs, clamp, sqrt, block-sum -> partial.
__global__ __launch_bounds__(TPB) void hausdorff_partial_kernel(
    const float* __restrict__ pmin, float* __restrict__ partial)
{
    int bid = blockIdx.x;
    int grp = bid & (GPB - 1);
    int g   = bid >> 2;            // dir*NB + batch
    int t   = threadIdx.x;
    int col = grp * CPB + t;       // float4 column, 0..1023

    const float4* base = reinterpret_cast<const float4*>(
        pmin + (size_t)g * NS * M) + col;

    float4 mn = make_float4(3.4e38f, 3.4e38f, 3.4e38f, 3.4e38f);
    #pragma unroll 8
    for (int s = 0; s < NS; ++s) {
        float4 v = base[(size_t)s * (M/4)];
        mn.x = fminf(mn.x, v.x); mn.y = fminf(mn.y, v.y);
        mn.z = fminf(mn.z, v.z); mn.w = fminf(mn.w, v.w);
    }
    float sum = sqrtf(fmaxf(mn.x, 0.0f)) + sqrtf(fmaxf(mn.y, 0.0f))
              + sqrtf(fmaxf(mn.z, 0.0f)) + sqrtf(fmaxf(mn.w, 0.0f));

    for (int off = 32; off > 0; off >>= 1)
        sum += __shfl_down(sum, off, 64);

    __shared__ float red[TPB / 64];
    if ((t & 63) == 0) red[t >> 6] = sum;
    __syncthreads();
    if (t == 0) {
        float tt = 0.0f;
        #pragma unroll
        for (int w = 0; w < TPB / 64; ++w) tt += red[w];
        partial[bid] = tt;         // partial[g*GPB + grp]
    }
}

// Stage 2b: out[b] = (sum over dirs & grps) / M.  1 block, 64 threads.
__global__ __launch_bounds__(64) void hausdorff_final_kernel(
    const float* __restrict__ partial, float* __restrict__ out)
{
    int t = threadIdx.x;
    if (t < NB) {
        float s = 0.0f;
        #pragma unroll
        for (int j = 0; j < GPB; ++j)
            s += partial[t * GPB + j] + partial[(NB + t) * GPB + j];
        out[t] = s * (1.0f / (float)M);
    }
}

extern "C" void kernel_launch(void* const* d_in, const int* in_sizes, int n_in,
                              void* d_out, int out_size, void* d_ws, size_t ws_size,
                              hipStream_t stream) {
    const float* set1 = (const float*)d_in[0];
    const float* set2 = (const float*)d_in[1];
    float* out     = (float*)d_out;
    float* pmin    = (float*)d_ws;                     // 2*NB*NS*M*4 = 8 MiB
    float* partial = pmin + (size_t)2 * NB * NS * M;   // 64 floats

    hausdorff_min_kernel<<<2 * NB * NS, TPB, 0, stream>>>(set1, set2, pmin);
    hausdorff_partial_kernel<<<2 * NB * GPB, TPB, 0, stream>>>(pmin, partial);
    hausdorff_final_kernel<<<1, 64, 0, stream>>>(partial, out);
}

// Round 8
// 32.428 us; speedup vs baseline: 4.4759x; 1.0232x over previous
//
#include <hip/hip_runtime.h>
#include <math.h>

// Problem constants (from reference): B=8, M=N=4096, C=3, f32.
constexpr int NB   = 8;
constexpr int M    = 4096;
constexpr int N    = 4096;
constexpr int NS   = 32;           // segments of the N loop
constexpr int SEG  = N / NS;       // 128 points per segment
constexpr int TPB  = 512;          // 8 waves/block
constexpr int KA   = 8;            // a-points per thread; TPB*KA = 4096 = M
constexpr int RTPB = 256;          // k2a threads
constexpr int GPB  = 4;            // k2a blocks per group g
constexpr int CPB  = (M / 4) / GPB;// float4 columns per k2a block = 256

// Stage 1: pmin[g][seg][a] = sa + min_{n in seg} (sb - 2 a.b)
// Identity: min_b ||a-b||^2 = sa + min_b (sb - 2 a.b) -> 3 fma + 1 min / pair.
// Shape A/B vs R6: same 512 blocks, but TPB=512 -> 16 waves/CU = 4 waves/SIMD
// (R6 was 2/SIMD). VGPR ~50 -> occupancy stays grid-limited, no spill.
// LDS per CU per n: 16 waves x 12 cyc = 192 < VALU 272 cyc/SIMD -> hidden.
__global__ __launch_bounds__(TPB, 2) void hausdorff_min_kernel(
    const float* __restrict__ set1, const float* __restrict__ set2,
    float* __restrict__ pmin)
{
    __shared__ float4 bpts[SEG];   // 2 KB: (-2x, -2y, -2z, |b|^2)

    int bid   = blockIdx.x;
    int seg   = bid & (NS - 1);
    int g     = bid >> 5;          // dir*NB + batch
    int batch = g & (NB - 1);
    int dir   = g >> 3;
    int tid   = threadIdx.x;

    const float* A  = dir ? set2 : set1;   // query set
    const float* Bs = dir ? set1 : set2;   // target set

    // Cooperative load + transform of the n-segment into LDS.
    const float* src = Bs + ((size_t)batch * N + (size_t)seg * SEG) * 3;
    for (int i = tid; i < SEG; i += TPB) {
        float x = src[i*3+0], y = src[i*3+1], z = src[i*3+2];
        float sb = fmaf(z, z, fmaf(y, y, x * x));
        bpts[i] = make_float4(-2.0f * x, -2.0f * y, -2.0f * z, sb);
    }
    __syncthreads();

    // This thread's KA query points in registers (block covers all of M).
    float ax[KA], ay[KA], az[KA], dmin[KA];
    const float* abase = A + (size_t)batch * M * 3;
    #pragma unroll
    for (int k = 0; k < KA; ++k) {
        int ai = k * TPB + tid;
        ax[k] = abase[ai*3+0];
        ay[k] = abase[ai*3+1];
        az[k] = abase[ai*3+2];
        dmin[k] = 3.4e38f;
    }

    #pragma unroll 8
    for (int n = 0; n < SEG; ++n) {
        float4 b = bpts[n];            // broadcast ds_read_b128
        #pragma unroll
        for (int k = 0; k < KA; ++k) {
            float d2 = fmaf(ax[k], b.x, fmaf(ay[k], b.y, fmaf(az[k], b.z, b.w)));
            dmin[k] = fminf(dmin[k], d2);
        }
    }

    // Epilogue: add query-constant |a|^2, coalesced stores [g][seg][a].
    float* outp = pmin + ((size_t)g * NS + seg) * M;
    #pragma unroll
    for (int k = 0; k < KA; ++k) {
        int ai = k * TPB + tid;
        float sa = fmaf(az[k], az[k], fmaf(ay[k], ay[k], ax[k] * ax[k]));
        outp[ai] = sa + dmin[k];
    }
}

// Stage 2a: grid = 16*GPB = 64 blocks x 256 threads; one float4-column per
// thread (coalesced), min over 32 segs, clamp, sqrt, block-sum -> partial.
__global__ __launch_bounds__(RTPB) void hausdorff_partial_kernel(
    const float* __restrict__ pmin, float* __restrict__ partial)
{
    int bid = blockIdx.x;
    int grp = bid & (GPB - 1);
    int g   = bid >> 2;            // dir*NB + batch
    int t   = threadIdx.x;
    int col = grp * CPB + t;       // float4 column, 0..1023

    const float4* base = reinterpret_cast<const float4*>(
        pmin + (size_t)g * NS * M) + col;

    float4 mn = make_float4(3.4e38f, 3.4e38f, 3.4e38f, 3.4e38f);
    #pragma unroll 8
    for (int s = 0; s < NS; ++s) {
        float4 v = base[(size_t)s * (M/4)];
        mn.x = fminf(mn.x, v.x); mn.y = fminf(mn.y, v.y);
        mn.z = fminf(mn.z, v.z); mn.w = fminf(mn.w, v.w);
    }
    float sum = sqrtf(fmaxf(mn.x, 0.0f)) + sqrtf(fmaxf(mn.y, 0.0f))
              + sqrtf(fmaxf(mn.z, 0.0f)) + sqrtf(fmaxf(mn.w, 0.0f));

    for (int off = 32; off > 0; off >>= 1)
        sum += __shfl_down(sum, off, 64);

    __shared__ float red[RTPB / 64];
    if ((t & 63) == 0) red[t >> 6] = sum;
    __syncthreads();
    if (t == 0) {
        float tt = 0.0f;
        #pragma unroll
        for (int w = 0; w < RTPB / 64; ++w) tt += red[w];
        partial[bid] = tt;         // partial[g*GPB + grp]
    }
}

// Stage 2b: out[b] = (sum over dirs & grps) / M.  1 block, 64 threads.
__global__ __launch_bounds__(64) void hausdorff_final_kernel(
    const float* __restrict__ partial, float* __restrict__ out)
{
    int t = threadIdx.x;
    if (t < NB) {
        float s = 0.0f;
        #pragma unroll
        for (int j = 0; j < GPB; ++j)
            s += partial[t * GPB + j] + partial[(NB + t) * GPB + j];
        out[t] = s * (1.0f / (float)M);
    }
}

extern "C" void kernel_launch(void* const* d_in, const int* in_sizes, int n_in,
                              void* d_out, int out_size, void* d_ws, size_t ws_size,
                              hipStream_t stream) {
    const float* set1 = (const float*)d_in[0];
    const float* set2 = (const float*)d_in[1];
    float* out     = (float*)d_out;
    float* pmin    = (float*)d_ws;                     // 2*NB*NS*M*4 = 8 MiB
    float* partial = pmin + (size_t)2 * NB * NS * M;   // 64 floats

    hausdorff_min_kernel<<<2 * NB * NS, TPB, 0, stream>>>(set1, set2, pmin);
    hausdorff_partial_kernel<<<2 * NB * GPB, RTPB, 0, stream>>>(pmin, partial);
    hausdorff_final_kernel<<<1, 64, 0, stream>>>(partial, out);
}